// Round 16
// baseline (317.829 us; speedup 1.0000x reference)
//
#include <hip/hip_runtime.h>

typedef unsigned short u16;
typedef __attribute__((ext_vector_type(8))) short short8;
typedef __attribute__((ext_vector_type(4))) float f32x4;
typedef __attribute__((ext_vector_type(4))) float floatx4;
typedef __attribute__((ext_vector_type(4))) unsigned short ushort4v;
typedef __attribute__((ext_vector_type(8))) unsigned short ushort8v;

#define MFMA(a, b, c)   __builtin_amdgcn_mfma_f32_16x16x32_bf16(a, b, c, 0, 0, 0)

__device__ __forceinline__ u16 f2bf(float f) {
    unsigned u = __float_as_uint(f);
    u += 0x7fffu + ((u >> 16) & 1u);   // RNE
    return (u16)(u >> 16);
}

__device__ __forceinline__ void async16(const void* g, void* l) {
    __builtin_amdgcn_global_load_lds(
        (const __attribute__((address_space(1))) void*)g,
        (__attribute__((address_space(3))) void*)l, 16, 0, 0);
}

// barrier-only phase boundary (no vmcnt): raw barrier + fences so ds_reads
// cannot hoist above it; compiler schedules its own lgkmcnt to MFMA.
#define PBAR do {                                                \
    __builtin_amdgcn_s_barrier();                                \
    asm volatile("" ::: "memory");                               \
    __builtin_amdgcn_sched_barrier(0);                           \
} while (0)

// ------- fp32 -> bf16 convert: x + 4 weight matrices in ONE launch --------
__global__ void cvt_all(const float* __restrict__ x,
                        const float* __restrict__ w0, const float* __restrict__ w1,
                        const float* __restrict__ w2, const float* __restrict__ w3,
                        u16* __restrict__ d, int nx4, int nw4) {
    int total = nx4 + 4 * nw4;
    int i = blockIdx.x * blockDim.x + threadIdx.x;
    int stride = gridDim.x * blockDim.x;
    for (; i < total; i += stride) {
        floatx4 v;
        if (i < nx4) {
            v = ((const floatx4*)x)[i];
        } else {
            int t = i - nx4;
            int w = t >> 18;             // nw4 = 2^18
            int j = t & (nw4 - 1);
            const float* s = w == 0 ? w0 : (w == 1 ? w1 : (w == 2 ? w2 : w3));
            v = ((const floatx4*)s)[j];
        }
        ushort4v o;
        o[0] = f2bf(v[0]); o[1] = f2bf(v[1]); o[2] = f2bf(v[2]); o[3] = f2bf(v[3]);
        ((ushort4v*)d)[i] = o;
    }
}

// ---------------- NT GEMM 256x256: C[M,N] = A[M,K] * B[N,K]^T --------------
// R1 skeleton (measured 42% MfmaUtil) with THINNED WAITS (T4): single
// vmcnt(4) per K-tile at p1 (retires exactly tile t's 8 loads), barriers only
// at p2/p3 (fence the buffer-overwrite hazards), p4 barrier-free. Staging
// lag-1.5: prologue = tile0 (8) + tile1 A0,B0 (4); per tile t: p1->A1(t+1),
// p2->B1(t+1), p3->A0(t+2), p4->B0(t+2). Every load flies ~4 phases (was
// 1-3); 2 of 3 per-tile wait points removed. Ledger: 12 outstanding at each
// p1, vmcnt(4) -> all of tile t confirmed + p1 barrier = cross-wave visible.
// Tail: t1/t2 clamp to NT-1 (dead writes into consumed halves); drain after.
template <bool BF16_OUT>
__global__ __launch_bounds__(512, 2) void gemm_nt(
    const u16* __restrict__ A, const u16* __restrict__ B0,
    const u16* __restrict__ B1, const u16* __restrict__ B2,
    void* __restrict__ Cv, int M, int N, int K)
{
    __shared__ u16 As[2][16384];   // [buf][row*64 + slot*8], 256 rows
    __shared__ u16 Bs[2][16384];
    const int tid = threadIdx.x;
    const int wave = tid >> 6, lane = tid & 63;
    const int tl = lane & 15, quad = lane >> 4, xr = lane & 7;
    const int wm = wave >> 2, wn = wave & 3;
    const int m0 = blockIdx.x * 256, n0 = blockIdx.y * 256;
    const u16* Bm = blockIdx.z == 0 ? B0 : (blockIdx.z == 1 ? B1 : B2);
    const size_t coff = (size_t)blockIdx.z * M * N;

    f32x4 acc[8][4];
#pragma unroll
    for (int i = 0; i < 8; i++)
#pragma unroll
        for (int j = 0; j < 4; j++) acc[i][j] = (f32x4)(0.0f);

    // ---- staging geometry (per-thread) ----
    const int rw = lane >> 3, sl = lane & 7;     // row-in-waveround, slot
    const int g = sl ^ rw;                       // pre-swizzled global chunk
    const u16* a_srcb = A  + (size_t)(m0 + wave * 8 + rw) * K + g * 8;
    const u16* b_srcb = Bm + (size_t)(n0 + (wave >> 2) * 64 + (wave & 3) * 8 + rw) * K + g * 8;
    u16* asd = &As[0][0] + wave * 512;                                  // wave-uniform
    u16* bsd = &Bs[0][0] + (wave >> 2) * 4096 + (wave & 3) * 512;       // wave-uniform

    // A half h: rows {h*64..h*64+63} U {128+h*64..+63}   (2 loads/thread)
#define STG_A(t, h, p) do {                                                              \
    async16(a_srcb + (size_t)((h) * 64) * K + (size_t)(t) * 64,                          \
            asd + (p) * 16384 + (h) * 4096);                                             \
    async16(a_srcb + (size_t)((h) * 64 + 128) * K + (size_t)(t) * 64,                    \
            asd + (p) * 16384 + (h) * 4096 + 8192);                                      \
} while (0)
    // B half h: rows with (row%64) in [h*32, h*32+32)
#define STG_B(t, h, p) do {                                                              \
    async16(b_srcb + (size_t)((h) * 32) * K + (size_t)(t) * 64,                          \
            bsd + (p) * 16384 + (h) * 2048);                                             \
    async16(b_srcb + (size_t)((h) * 32 + 128) * K + (size_t)(t) * 64,                    \
            bsd + (p) * 16384 + (h) * 2048 + 8192);                                      \
} while (0)

    const int NT = K >> 6;
    // fragment read bases: A row = wm*128 + mf*16 + tl ; B row = wn*64 + nf*16 + tl
    const u16* Ab0 = &As[0][0] + (wm * 128 + tl) * 64;
    const u16* Bb0 = &Bs[0][0] + (wn * 64 + tl) * 64;
    const int s0 = (quad ^ xr) * 8;              // kh=0 ; kh=1 -> s0^32

    short8 afA[4][2], afB[4][2], bfA[2][2], bfB[2][2];

    // prologue: tile0 all 4 halves + tile1 A0,B0 (12 loads outstanding)
    STG_A(0, 0, 0); STG_B(0, 0, 0); STG_A(0, 1, 0); STG_B(0, 1, 0);
    STG_A(1, 0, 1); STG_B(1, 0, 1);

    for (int t = 0; t < NT; ++t) {
        const int p = t & 1;
        const int t1 = (t + 1 < NT) ? t + 1 : NT - 1;
        const int t2 = (t + 2 < NT) ? t + 2 : NT - 1;
        const int b1 = (t + 1) & 1, b2 = t & 1;
        const u16* Ab = Ab0 + p * 16384;
        const u16* Bb = Bb0 + p * 16384;

        // ---- p1: vmcnt(4) retires ALL of tile t (8 loads); reads A0+B0;
        //          stage A1(t+1); MFMA quad(0,0) ----
        asm volatile("s_waitcnt vmcnt(4)" ::: "memory");
        PBAR;
#pragma unroll
        for (int i = 0; i < 4; i++) {
            afA[i][0] = *(const short8*)(Ab + i * 1024 + s0);
            afA[i][1] = *(const short8*)(Ab + i * 1024 + (s0 ^ 32));
        }
#pragma unroll
        for (int j = 0; j < 2; j++) {
            bfA[j][0] = *(const short8*)(Bb + j * 1024 + s0);
            bfA[j][1] = *(const short8*)(Bb + j * 1024 + (s0 ^ 32));
        }
        STG_A(t1, 1, b1);
        __builtin_amdgcn_s_setprio(1);
#pragma unroll
        for (int kh = 0; kh < 2; kh++)
#pragma unroll
            for (int i = 0; i < 4; i++)
#pragma unroll
                for (int j = 0; j < 2; j++)
                    acc[i][j] = MFMA(afA[i][kh], bfA[j][kh], acc[i][j]);
        __builtin_amdgcn_s_setprio(0);

        // ---- p2: barrier only (fences p3's overwrite); reads A1;
        //          stage B1(t+1); MFMA quad(1,0) ----
        PBAR;
#pragma unroll
        for (int i = 0; i < 4; i++) {
            afB[i][0] = *(const short8*)(Ab + (4 + i) * 1024 + s0);
            afB[i][1] = *(const short8*)(Ab + (4 + i) * 1024 + (s0 ^ 32));
        }
        STG_B(t1, 1, b1);
        __builtin_amdgcn_s_setprio(1);
#pragma unroll
        for (int kh = 0; kh < 2; kh++)
#pragma unroll
            for (int i = 0; i < 4; i++)
#pragma unroll
                for (int j = 0; j < 2; j++)
                    acc[4 + i][j] = MFMA(afB[i][kh], bfA[j][kh], acc[4 + i][j]);
        __builtin_amdgcn_s_setprio(0);

        // ---- p3: barrier only; reads B1; stage A0(t+2) (overwrites current
        //          A-half0 — all waves past p1 reads via p2 barrier);
        //          MFMA quad(1,1) ----
        PBAR;
#pragma unroll
        for (int j = 0; j < 2; j++) {
            bfB[j][0] = *(const short8*)(Bb + (2 + j) * 1024 + s0);
            bfB[j][1] = *(const short8*)(Bb + (2 + j) * 1024 + (s0 ^ 32));
        }
        STG_A(t2, 0, b2);
        __builtin_amdgcn_s_setprio(1);
#pragma unroll
        for (int kh = 0; kh < 2; kh++)
#pragma unroll
            for (int i = 0; i < 4; i++)
#pragma unroll
                for (int j = 0; j < 2; j++)
                    acc[4 + i][2 + j] = MFMA(afB[i][kh], bfB[j][kh], acc[4 + i][2 + j]);
        __builtin_amdgcn_s_setprio(0);

        // ---- p4: no barrier (overwrite of current B-half0 fenced by p3);
        //          stage B0(t+2); MFMA quad(0,1) ----
        STG_B(t2, 0, b2);
        __builtin_amdgcn_s_setprio(1);
#pragma unroll
        for (int kh = 0; kh < 2; kh++)
#pragma unroll
            for (int i = 0; i < 4; i++)
#pragma unroll
                for (int j = 0; j < 2; j++)
                    acc[i][2 + j] = MFMA(afA[i][kh], bfB[j][kh], acc[i][2 + j]);
        __builtin_amdgcn_s_setprio(0);
    }
#undef STG_A
#undef STG_B
    asm volatile("s_waitcnt vmcnt(0)" ::: "memory");   // drain tail dummies

    // epilogue: 16x16 C/D layout col=lane&15, row=quad*4+r
#pragma unroll
    for (int mf = 0; mf < 8; mf++)
#pragma unroll
        for (int nf = 0; nf < 4; nf++)
#pragma unroll
            for (int r = 0; r < 4; r++) {
                int row = m0 + wm * 128 + mf * 16 + quad * 4 + r;
                int col = n0 + wn * 64 + nf * 16 + tl;
                if constexpr (BF16_OUT)
                    ((u16*)Cv)[coff + (size_t)row * N + col] = f2bf(acc[mf][nf][r]);
                else
                    ((float*)Cv)[coff + (size_t)row * N + col] = acc[mf][nf][r];
            }
}

// ---------------- fused windowed attention (merged halves) ----------------
// FROZEN (R15 source, ~56us; R12 variants equal within noise). One block per
// (b,h,window): 128 q, 192 keys, 8 waves; V,K staged concurrently (vmcnt(3));
// S^T = K q^T; in-lane softmax; P overlay in Vs/Ks XOR-swizzled; both
// barriers around the P-write.
__global__ __launch_bounds__(512, 4) void attn_win(
    const u16* __restrict__ qkv, u16* __restrict__ outb)
{
    constexpr int T = 8192, D = 1024, HD = 64, G = 64, WIN = 128;
    constexpr int MTOT = 2 * T;
    __shared__ u16 Vs[192 * 64];   // V packed [key][dim]; later P rows 0-63
    __shared__ u16 Ks[192 * 64];   // K swizzled [key][slot]; later P rows 64-127
    __shared__ u16 Vt[64 * 200];   // V^T [dim][key], stride 200

    const int blk = blockIdx.x;
    const int nwin = blk & 63;
    const int h = (blk >> 6) & 15;
    const int b = blk >> 10;
    const int tid = threadIdx.x;
    const int wave = tid >> 6, lane = tid & 63;
    const int quad = lane >> 4, tl = lane & 15;
    const int win0 = nwin * WIN;
    const size_t brow = (size_t)b * T;
    const u16* qb = qkv;
    const u16* kb = qkv + (size_t)MTOT * D;
    const u16* vb = qkv + (size_t)2 * MTOT * D;

    // q fragments first (so vmcnt(3) retires them along with V, leaving only K)
    short8 bq[2];
    {
        int tok = win0 + wave * 16 + tl;
        const u16* qrow = qb + (brow + tok) * D + h * HD;
        bq[0] = *(const short8*)(qrow + quad * 8);
        bq[1] = *(const short8*)(qrow + 32 + quad * 8);
    }
    __builtin_amdgcn_sched_barrier(0);   // pin q-loads before staging

    // stage V packed [key][dim] (linear, wave-uniform dest), 3 loads/thread
#pragma unroll
    for (int i = 0; i < 3; i++) {
        int ch = i * 512 + tid;
        int row = ch >> 3, c = ch & 7;
        int tok = row < G ? row : win0 + (row - G);
        async16(vb + (brow + tok) * D + h * HD + c * 8,
                Vs + (i * 512 + wave * 64) * 8);
    }
    // stage K, swizzled source chunk g = slot ^ (row&7), 3 loads/thread
#pragma unroll
    for (int i = 0; i < 3; i++) {
        int ch = i * 512 + tid;
        int row = ch >> 3, slot = ch & 7;
        int gg = slot ^ (row & 7);
        int tok = row < G ? row : win0 + (row - G);
        async16(kb + (brow + tok) * D + h * HD + gg * 8,
                Ks + (i * 512 + wave * 64) * 8);
    }

    asm volatile("s_waitcnt vmcnt(3)" ::: "memory");   // q + V landed; K in flight
    __builtin_amdgcn_s_barrier();
    __builtin_amdgcn_sched_barrier(0);

    // transpose Vs[key][dim] -> Vt[dim][key] (overlaps K's HBM latency)
    {
        const int d = lane;
#pragma unroll
        for (int i = 0; i < 3; i++) {
            int c = wave * 3 + i;   // key-chunk 0..23
            ushort8v v;
#pragma unroll
            for (int j = 0; j < 8; j++) v[j] = Vs[(c * 8 + j) * 64 + d];
            *(ushort8v*)&Vt[d * 200 + c * 8] = v;
        }
    }

    asm volatile("s_waitcnt vmcnt(0) lgkmcnt(0)" ::: "memory");  // K + Vt done
    __builtin_amdgcn_s_barrier();
    __builtin_amdgcn_sched_barrier(0);

    // S^T = K q^T : 12 key-tiles x 1 query-tile per wave
    f32x4 s[12];
#pragma unroll
    for (int kt = 0; kt < 12; kt++) s[kt] = (f32x4)(0.0f);
#pragma unroll
    for (int kt = 0; kt < 12; kt++) {
        int row = kt * 16 + tl;
        int sa = quad ^ (tl & 7);
        int sb = (4 + quad) ^ (tl & 7);
        short8 a0 = *(const short8*)&Ks[row * 64 + sa * 8];
        short8 a1 = *(const short8*)&Ks[row * 64 + sb * 8];
        s[kt] = MFMA(a0, bq[0], s[kt]);
        s[kt] = MFMA(a1, bq[1], s[kt]);
    }

    // softmax over keys for query col=tl: in-lane 48 values + 2 quad shuffles
    const float c1 = 0.125f * 1.4426950408889634f;  // scale * log2(e)
    float mx = -1e30f;
#pragma unroll
    for (int kt = 0; kt < 12; kt++)
#pragma unroll
        for (int r = 0; r < 4; r++) mx = fmaxf(mx, s[kt][r]);
    mx = fmaxf(mx, __shfl_xor(mx, 16, 64));
    mx = fmaxf(mx, __shfl_xor(mx, 32, 64));
    float sum = 0.f;
#pragma unroll
    for (int kt = 0; kt < 12; kt++)
#pragma unroll
        for (int r = 0; r < 4; r++) {
            float e = exp2f((s[kt][r] - mx) * c1);
            s[kt][r] = e;
            sum += e;
        }
    sum += __shfl_xor(sum, 16, 64);
    sum += __shfl_xor(sum, 32, 64);
    float inv = 1.f / sum;

    __syncthreads();   // all waves done reading Ks/Vs before P overwrites

    // write P: row lq = wave*16+tl holds P[q=lq][key]; key k at swizzled
    // slot (k>>3)^(lq&7), offset k&7. ushort4 at k = kt*16 + quad*4.
    const int lq = wave * 16 + tl;
    u16* Pr = (lq < 64) ? (Vs + lq * 192) : (Ks + (lq - 64) * 192);
#pragma unroll
    for (int kt = 0; kt < 12; kt++) {
        ushort4v pk;
#pragma unroll
        for (int r = 0; r < 4; r++) pk[r] = f2bf(s[kt][r] * inv);
        *(ushort4v*)&Pr[((((kt * 2) + (quad >> 1)) ^ (lq & 7)) << 3) + ((quad & 1) << 2)] = pk;
    }
    __syncthreads();

    // out = P V : 1 query-tile x 4 dim-tiles per wave, K=192
    f32x4 o[4];
#pragma unroll
    for (int dt = 0; dt < 4; dt++) o[dt] = (f32x4)(0.0f);
#pragma unroll
    for (int ks = 0; ks < 6; ks++) {
        short8 pa = *(const short8*)&Pr[(((ks * 4) + quad) ^ (lq & 7)) << 3];
#pragma unroll
        for (int dt = 0; dt < 4; dt++) {
            short8 vv = *(const short8*)&Vt[(dt * 16 + tl) * 200 + ks * 32 + quad * 8];
            o[dt] = MFMA(pa, vv, o[dt]);
        }
    }

    // epilogue: D[m=query][n=dim], row=quad*4+r, col=tl
#pragma unroll
    for (int dt = 0; dt < 4; dt++)
#pragma unroll
        for (int r = 0; r < 4; r++) {
            int qq = win0 + wave * 16 + quad * 4 + r;
            int dim = dt * 16 + tl;
            outb[(brow + qq) * D + h * HD + dim] = f2bf(o[dt][r]);
        }
}

extern "C" void kernel_launch(void* const* d_in, const int* in_sizes, int n_in,
                              void* d_out, int out_size, void* d_ws, size_t ws_size,
                              hipStream_t stream)
{
    const float* x  = (const float*)d_in[0];
    const float* Wq = (const float*)d_in[1];
    const float* Wk = (const float*)d_in[2];
    const float* Wv = (const float*)d_in[3];
    const float* Wo = (const float*)d_in[4];

    const int M = 16384, D = 1024;   // M = B*T
    u16* xb  = (u16*)d_ws;                  // M*D
    u16* wqb = xb  + (size_t)M * D;         // D*D each (q,k,v contiguous)
    u16* wob = wqb + (size_t)3 * D * D;
    u16* qkv = wob + (size_t)D * D;         // 3*M*D (q,k,v)
    u16* att = qkv + (size_t)3 * M * D;     // M*D

    cvt_all<<<2560, 256, 0, stream>>>(x, Wq, Wk, Wv, Wo, xb,
                                      M * D / 4, D * D / 4);

    gemm_nt<true ><<<dim3(M / 256, D / 256, 3), 512, 0, stream>>>(
        xb, wqb, wqb + (size_t)D * D, wqb + (size_t)2 * D * D, qkv, M, D, D);
    attn_win<<<dim3(2048), 512, 0, stream>>>(qkv, att);
    gemm_nt<false><<<dim3(M / 256, D / 256, 1), 512, 0, stream>>>(
        att, wob, wob, wob, d_out, M, D, D);
}

// Round 17
// 297.197 us; speedup vs baseline: 1.0694x; 1.0694x over previous
//
#include <hip/hip_runtime.h>

typedef unsigned short u16;
typedef __attribute__((ext_vector_type(8))) short short8;
typedef __attribute__((ext_vector_type(4))) float f32x4;
typedef __attribute__((ext_vector_type(4))) float floatx4;
typedef __attribute__((ext_vector_type(4))) unsigned short ushort4v;
typedef __attribute__((ext_vector_type(8))) unsigned short ushort8v;

#define MFMA(a, b, c)   __builtin_amdgcn_mfma_f32_16x16x32_bf16(a, b, c, 0, 0, 0)

__device__ __forceinline__ u16 f2bf(float f) {
    unsigned u = __float_as_uint(f);
    u += 0x7fffu + ((u >> 16) & 1u);   // RNE
    return (u16)(u >> 16);
}

__device__ __forceinline__ void async16(const void* g, void* l) {
    __builtin_amdgcn_global_load_lds(
        (const __attribute__((address_space(1))) void*)g,
        (__attribute__((address_space(3))) void*)l, 16, 0, 0);
}

// counted-vmcnt phase sync — R1 structure, the measured LOCAL OPTIMUM (42%
// MfmaUtil). Both restructurings refuted on HW: drain-per-phase (R2: 34.5%)
// and single-wait-per-tile (R16: 36.8%). Wait own prefetches to N, raw
// barrier, fence; ds_reads AFTER the sync so the compiler schedules
// fine-grained lgkmcnt between ds_read and MFMA.
#define SYNC(n) do {                                             \
    asm volatile("s_waitcnt vmcnt(" #n ")" ::: "memory");        \
    __builtin_amdgcn_s_barrier();                                \
    asm volatile("" ::: "memory");                               \
    __builtin_amdgcn_sched_barrier(0);                           \
} while (0)

// ------- fp32 -> bf16 convert: x + 4 weight matrices in ONE launch --------
// 116 MB of traffic at ~19us == HBM BW floor; closed.
__global__ void cvt_all(const float* __restrict__ x,
                        const float* __restrict__ w0, const float* __restrict__ w1,
                        const float* __restrict__ w2, const float* __restrict__ w3,
                        u16* __restrict__ d, int nx4, int nw4) {
    int total = nx4 + 4 * nw4;
    int i = blockIdx.x * blockDim.x + threadIdx.x;
    int stride = gridDim.x * blockDim.x;
    for (; i < total; i += stride) {
        floatx4 v;
        if (i < nx4) {
            v = ((const floatx4*)x)[i];
        } else {
            int t = i - nx4;
            int w = t >> 18;             // nw4 = 2^18
            int j = t & (nw4 - 1);
            const float* s = w == 0 ? w0 : (w == 1 ? w1 : (w == 2 ? w2 : w3));
            v = ((const floatx4*)s)[j];
        }
        ushort4v o;
        o[0] = f2bf(v[0]); o[1] = f2bf(v[1]); o[2] = f2bf(v[2]); o[3] = f2bf(v[3]);
        ((ushort4v*)d)[i] = o;
    }
}

// ---------------- NT GEMM 256x256: C[M,N] = A[M,K] * B[N,K]^T --------------
// CONVERGED (R1 structure; measured 103.6-105.0us QKV across runs, MfmaUtil
// ~42%, bank conflicts 0). 256x256 tile, BK=64, 8 waves (2M x 4N), per-wave
// 128x64 C as 8x4 frags of 16x16x32 MFMA. Per K-tile 4 phases: {SYNC(counted
// vmcnt + single barrier) | ds_read one A/B subtile | stage one half-tile of
// t+1 | 16 MFMA under setprio(1)}. Chunk-slot involution slot = g ^ (row&7)
// on the GLOBAL source + fragment reads keeps LDS dest linear (conflict-free,
// measured). Used for QKV (z=3) and proj (z=1).
template <bool BF16_OUT>
__global__ __launch_bounds__(512, 2) void gemm_nt(
    const u16* __restrict__ A, const u16* __restrict__ B0,
    const u16* __restrict__ B1, const u16* __restrict__ B2,
    void* __restrict__ Cv, int M, int N, int K)
{
    __shared__ u16 As[2][16384];   // [buf][row*64 + slot*8], 256 rows
    __shared__ u16 Bs[2][16384];
    const int tid = threadIdx.x;
    const int wave = tid >> 6, lane = tid & 63;
    const int tl = lane & 15, quad = lane >> 4, xr = lane & 7;
    const int wm = wave >> 2, wn = wave & 3;
    const int m0 = blockIdx.x * 256, n0 = blockIdx.y * 256;
    const u16* Bm = blockIdx.z == 0 ? B0 : (blockIdx.z == 1 ? B1 : B2);
    const size_t coff = (size_t)blockIdx.z * M * N;

    f32x4 acc[8][4];
#pragma unroll
    for (int i = 0; i < 8; i++)
#pragma unroll
        for (int j = 0; j < 4; j++) acc[i][j] = (f32x4)(0.0f);

    // ---- staging geometry (per-thread) ----
    const int rw = lane >> 3, sl = lane & 7;     // row-in-waveround, slot
    const int g = sl ^ rw;                       // pre-swizzled global chunk
    const u16* a_srcb = A  + (size_t)(m0 + wave * 8 + rw) * K + g * 8;
    const u16* b_srcb = Bm + (size_t)(n0 + (wave >> 2) * 64 + (wave & 3) * 8 + rw) * K + g * 8;
    u16* asd = &As[0][0] + wave * 512;                                  // wave-uniform
    u16* bsd = &Bs[0][0] + (wave >> 2) * 4096 + (wave & 3) * 512;       // wave-uniform

    // A half h: rows {h*64..h*64+63} U {128+h*64..+63}   (2 loads/thread)
#define STG_A(t, h, p) do {                                                              \
    async16(a_srcb + (size_t)((h) * 64) * K + (size_t)(t) * 64,                          \
            asd + (p) * 16384 + (h) * 4096);                                             \
    async16(a_srcb + (size_t)((h) * 64 + 128) * K + (size_t)(t) * 64,                    \
            asd + (p) * 16384 + (h) * 4096 + 8192);                                      \
} while (0)
    // B half h: rows with (row%64) in [h*32, h*32+32)
#define STG_B(t, h, p) do {                                                              \
    async16(b_srcb + (size_t)((h) * 32) * K + (size_t)(t) * 64,                          \
            bsd + (p) * 16384 + (h) * 2048);                                             \
    async16(b_srcb + (size_t)((h) * 32 + 128) * K + (size_t)(t) * 64,                    \
            bsd + (p) * 16384 + (h) * 2048 + 8192);                                      \
} while (0)

    const int NT = K >> 6;
    // fragment read bases: A row = wm*128 + mf*16 + tl ; B row = wn*64 + nf*16 + tl
    const u16* Ab0 = &As[0][0] + (wm * 128 + tl) * 64;
    const u16* Bb0 = &Bs[0][0] + (wn * 64 + tl) * 64;
    const int s0 = (quad ^ xr) * 8;              // kh=0 ; kh=1 -> s0^32

    short8 afA[4][2], afB[4][2], bfA[2][2], bfB[2][2];

    // prologue: tile 0 -> buf 0 ; per-wave queue: A0,B0,A1,B1 (8 loads)
    STG_A(0, 0, 0); STG_B(0, 0, 0); STG_A(0, 1, 0); STG_B(0, 1, 0);

    for (int t = 0; t < NT; ++t) {
        const int p = t & 1, pq = p ^ 1;
        const bool pf = (t + 1) < NT;
        const u16* Ab = Ab0 + p * 16384;
        const u16* Bb = Bb0 + p * 16384;

        // ---- phase 1: A-half0 + B-half0 reads, quad(0,0) ----
        SYNC(4);                                  // A0(t), B0(t) landed
#pragma unroll
        for (int i = 0; i < 4; i++) {
            afA[i][0] = *(const short8*)(Ab + i * 1024 + s0);
            afA[i][1] = *(const short8*)(Ab + i * 1024 + (s0 ^ 32));
        }
#pragma unroll
        for (int j = 0; j < 2; j++) {
            bfA[j][0] = *(const short8*)(Bb + j * 1024 + s0);
            bfA[j][1] = *(const short8*)(Bb + j * 1024 + (s0 ^ 32));
        }
        if (pf) STG_A(t + 1, 0, pq);
        __builtin_amdgcn_s_setprio(1);
#pragma unroll
        for (int kh = 0; kh < 2; kh++)
#pragma unroll
            for (int i = 0; i < 4; i++)
#pragma unroll
                for (int j = 0; j < 2; j++)
                    acc[i][j] = MFMA(afA[i][kh], bfA[j][kh], acc[i][j]);
        __builtin_amdgcn_s_setprio(0);

        // ---- phase 2: A-half1 reads, quad(1,0) ----
        if (pf) { SYNC(4); } else { SYNC(2); }    // A1(t) landed
#pragma unroll
        for (int i = 0; i < 4; i++) {
            afB[i][0] = *(const short8*)(Ab + (4 + i) * 1024 + s0);
            afB[i][1] = *(const short8*)(Ab + (4 + i) * 1024 + (s0 ^ 32));
        }
        if (pf) STG_B(t + 1, 0, pq);
        __builtin_amdgcn_s_setprio(1);
#pragma unroll
        for (int kh = 0; kh < 2; kh++)
#pragma unroll
            for (int i = 0; i < 4; i++)
#pragma unroll
                for (int j = 0; j < 2; j++)
                    acc[4 + i][j] = MFMA(afB[i][kh], bfA[j][kh], acc[4 + i][j]);
        __builtin_amdgcn_s_setprio(0);

        // ---- phase 3: B-half1 reads, quad(1,1) ----
        if (pf) { SYNC(4); } else { SYNC(0); }    // B1(t) landed
#pragma unroll
        for (int j = 0; j < 2; j++) {
            bfB[j][0] = *(const short8*)(Bb + (2 + j) * 1024 + s0);
            bfB[j][1] = *(const short8*)(Bb + (2 + j) * 1024 + (s0 ^ 32));
        }
        if (pf) STG_A(t + 1, 1, pq);
        __builtin_amdgcn_s_setprio(1);
#pragma unroll
        for (int kh = 0; kh < 2; kh++)
#pragma unroll
            for (int i = 0; i < 4; i++)
#pragma unroll
                for (int j = 0; j < 2; j++)
                    acc[4 + i][2 + j] = MFMA(afB[i][kh], bfB[j][kh], acc[4 + i][2 + j]);
        __builtin_amdgcn_s_setprio(0);

        // ---- phase 4: no reads, quad(0,1) ----
        if (pf) STG_B(t + 1, 1, pq);
        __builtin_amdgcn_s_setprio(1);
#pragma unroll
        for (int kh = 0; kh < 2; kh++)
#pragma unroll
            for (int i = 0; i < 4; i++)
#pragma unroll
                for (int j = 0; j < 2; j++)
                    acc[i][2 + j] = MFMA(afA[i][kh], bfB[j][kh], acc[i][2 + j]);
        __builtin_amdgcn_s_setprio(0);
    }
#undef STG_A
#undef STG_B

    // epilogue: 16x16 C/D layout col=lane&15, row=quad*4+r
#pragma unroll
    for (int mf = 0; mf < 8; mf++)
#pragma unroll
        for (int nf = 0; nf < 4; nf++)
#pragma unroll
            for (int r = 0; r < 4; r++) {
                int row = m0 + wm * 128 + mf * 16 + quad * 4 + r;
                int col = n0 + wn * 64 + nf * 16 + tl;
                if constexpr (BF16_OUT)
                    ((u16*)Cv)[coff + (size_t)row * N + col] = f2bf(acc[mf][nf][r]);
                else
                    ((float*)Cv)[coff + (size_t)row * N + col] = acc[mf][nf][r];
            }
}

// ---------------- fused windowed attention (merged halves) ----------------
// CONVERGED (~56us; R6/R12/R15 variants within +-1us noise; setprio/cvtpk/
// barrier-removal grafts all neutral-to-negative). One block per (b,h,window):
// 128 q, 192 keys, 8 waves; V,K staged concurrently (vmcnt(3) lets V->Vt
// transpose run under K's flight); S^T = K q^T so softmax is in-lane + 2
// shuffles; P overlay in Vs/Ks XOR-swizzled; both barriers around P-write.
__global__ __launch_bounds__(512, 4) void attn_win(
    const u16* __restrict__ qkv, u16* __restrict__ outb)
{
    constexpr int T = 8192, D = 1024, HD = 64, G = 64, WIN = 128;
    constexpr int MTOT = 2 * T;
    __shared__ u16 Vs[192 * 64];   // V packed [key][dim]; later P rows 0-63
    __shared__ u16 Ks[192 * 64];   // K swizzled [key][slot]; later P rows 64-127
    __shared__ u16 Vt[64 * 200];   // V^T [dim][key], stride 200

    const int blk = blockIdx.x;
    const int nwin = blk & 63;
    const int h = (blk >> 6) & 15;
    const int b = blk >> 10;
    const int tid = threadIdx.x;
    const int wave = tid >> 6, lane = tid & 63;
    const int quad = lane >> 4, tl = lane & 15;
    const int win0 = nwin * WIN;
    const size_t brow = (size_t)b * T;
    const u16* qb = qkv;
    const u16* kb = qkv + (size_t)MTOT * D;
    const u16* vb = qkv + (size_t)2 * MTOT * D;

    // q fragments first (so vmcnt(3) retires them along with V, leaving only K)
    short8 bq[2];
    {
        int tok = win0 + wave * 16 + tl;
        const u16* qrow = qb + (brow + tok) * D + h * HD;
        bq[0] = *(const short8*)(qrow + quad * 8);
        bq[1] = *(const short8*)(qrow + 32 + quad * 8);
    }
    __builtin_amdgcn_sched_barrier(0);   // pin q-loads before staging

    // stage V packed [key][dim] (linear, wave-uniform dest), 3 loads/thread
#pragma unroll
    for (int i = 0; i < 3; i++) {
        int ch = i * 512 + tid;
        int row = ch >> 3, c = ch & 7;
        int tok = row < G ? row : win0 + (row - G);
        async16(vb + (brow + tok) * D + h * HD + c * 8,
                Vs + (i * 512 + wave * 64) * 8);
    }
    // stage K, swizzled source chunk g = slot ^ (row&7), 3 loads/thread
#pragma unroll
    for (int i = 0; i < 3; i++) {
        int ch = i * 512 + tid;
        int row = ch >> 3, slot = ch & 7;
        int gg = slot ^ (row & 7);
        int tok = row < G ? row : win0 + (row - G);
        async16(kb + (brow + tok) * D + h * HD + gg * 8,
                Ks + (i * 512 + wave * 64) * 8);
    }

    asm volatile("s_waitcnt vmcnt(3)" ::: "memory");   // q + V landed; K in flight
    __builtin_amdgcn_s_barrier();
    __builtin_amdgcn_sched_barrier(0);

    // transpose Vs[key][dim] -> Vt[dim][key] (overlaps K's HBM latency)
    {
        const int d = lane;
#pragma unroll
        for (int i = 0; i < 3; i++) {
            int c = wave * 3 + i;   // key-chunk 0..23
            ushort8v v;
#pragma unroll
            for (int j = 0; j < 8; j++) v[j] = Vs[(c * 8 + j) * 64 + d];
            *(ushort8v*)&Vt[d * 200 + c * 8] = v;
        }
    }

    asm volatile("s_waitcnt vmcnt(0) lgkmcnt(0)" ::: "memory");  // K + Vt done
    __builtin_amdgcn_s_barrier();
    __builtin_amdgcn_sched_barrier(0);

    // S^T = K q^T : 12 key-tiles x 1 query-tile per wave
    f32x4 s[12];
#pragma unroll
    for (int kt = 0; kt < 12; kt++) s[kt] = (f32x4)(0.0f);
#pragma unroll
    for (int kt = 0; kt < 12; kt++) {
        int row = kt * 16 + tl;
        int sa = quad ^ (tl & 7);
        int sb = (4 + quad) ^ (tl & 7);
        short8 a0 = *(const short8*)&Ks[row * 64 + sa * 8];
        short8 a1 = *(const short8*)&Ks[row * 64 + sb * 8];
        s[kt] = MFMA(a0, bq[0], s[kt]);
        s[kt] = MFMA(a1, bq[1], s[kt]);
    }

    // softmax over keys for query col=tl: in-lane 48 values + 2 quad shuffles
    const float c1 = 0.125f * 1.4426950408889634f;  // scale * log2(e)
    float mx = -1e30f;
#pragma unroll
    for (int kt = 0; kt < 12; kt++)
#pragma unroll
        for (int r = 0; r < 4; r++) mx = fmaxf(mx, s[kt][r]);
    mx = fmaxf(mx, __shfl_xor(mx, 16, 64));
    mx = fmaxf(mx, __shfl_xor(mx, 32, 64));
    float sum = 0.f;
#pragma unroll
    for (int kt = 0; kt < 12; kt++)
#pragma unroll
        for (int r = 0; r < 4; r++) {
            float e = exp2f((s[kt][r] - mx) * c1);
            s[kt][r] = e;
            sum += e;
        }
    sum += __shfl_xor(sum, 16, 64);
    sum += __shfl_xor(sum, 32, 64);
    float inv = 1.f / sum;

    __syncthreads();   // all waves done reading Ks/Vs before P overwrites

    // write P: row lq = wave*16+tl holds P[q=lq][key]; key k at swizzled
    // slot (k>>3)^(lq&7), offset k&7. ushort4 at k = kt*16 + quad*4.
    const int lq = wave * 16 + tl;
    u16* Pr = (lq < 64) ? (Vs + lq * 192) : (Ks + (lq - 64) * 192);
#pragma unroll
    for (int kt = 0; kt < 12; kt++) {
        ushort4v pk;
#pragma unroll
        for (int r = 0; r < 4; r++) pk[r] = f2bf(s[kt][r] * inv);
        *(ushort4v*)&Pr[((((kt * 2) + (quad >> 1)) ^ (lq & 7)) << 3) + ((quad & 1) << 2)] = pk;
    }
    __syncthreads();

    // out = P V : 1 query-tile x 4 dim-tiles per wave, K=192
    f32x4 o[4];
#pragma unroll
    for (int dt = 0; dt < 4; dt++) o[dt] = (f32x4)(0.0f);
#pragma unroll
    for (int ks = 0; ks < 6; ks++) {
        short8 pa = *(const short8*)&Pr[(((ks * 4) + quad) ^ (lq & 7)) << 3];
#pragma unroll
        for (int dt = 0; dt < 4; dt++) {
            short8 vv = *(const short8*)&Vt[(dt * 16 + tl) * 200 + ks * 32 + quad * 8];
            o[dt] = MFMA(pa, vv, o[dt]);
        }
    }

    // epilogue: D[m=query][n=dim], row=quad*4+r, col=tl
#pragma unroll
    for (int dt = 0; dt < 4; dt++)
#pragma unroll
        for (int r = 0; r < 4; r++) {
            int qq = win0 + wave * 16 + quad * 4 + r;
            int dim = dt * 16 + tl;
            outb[(brow + qq) * D + h * HD + dim] = f2bf(o[dt][r]);
        }
}

extern "C" void kernel_launch(void* const* d_in, const int* in_sizes, int n_in,
                              void* d_out, int out_size, void* d_ws, size_t ws_size,
                              hipStream_t stream)
{
    const float* x  = (const float*)d_in[0];
    const float* Wq = (const float*)d_in[1];
    const float* Wk = (const float*)d_in[2];
    const float* Wv = (const float*)d_in[3];
    const float* Wo = (const float*)d_in[4];

    const int M = 16384, D = 1024;   // M = B*T
    u16* xb  = (u16*)d_ws;                  // M*D
    u16* wqb = xb  + (size_t)M * D;         // D*D each (q,k,v contiguous)
    u16* wob = wqb + (size_t)3 * D * D;
    u16* qkv = wob + (size_t)D * D;         // 3*M*D (q,k,v)
    u16* att = qkv + (size_t)3 * M * D;     // M*D

    cvt_all<<<2560, 256, 0, stream>>>(x, Wq, Wk, Wv, Wo, xb,
                                      M * D / 4, D * D / 4);

    gemm_nt<true ><<<dim3(M / 256, D / 256, 3), 512, 0, stream>>>(
        xb, wqb, wqb + (size_t)D * D, wqb + (size_t)2 * D * D, qkv, M, D, D);
    attn_win<<<dim3(2048), 512, 0, stream>>>(qkv, att);
    gemm_nt<false><<<dim3(M / 256, D / 256, 1), 512, 0, stream>>>(
        att, wob, wob, wob, d_out, M, D, D);
}